// Round 9
// baseline (242.689 us; speedup 1.0000x reference)
//
#include <hip/hip_runtime.h>
#include <stdint.h>

// PoolingNms: 3 chained pool/unpool passes (k=3,5,6) on 16x1x1080x1920 fp32.
// lcm(3,5,6)=30 -> every 30x30 tile independent.
//
// [R7/R8 both died with "container failed twice" (no compile/absmax/counter
//  evidence). R7 differed from the clean R6 run in 3 ingredients:
//  launch_bounds(256,4), sched_barrier(0), and a 64-bit __shfl overload.
//  This round decouples: R6's EXACT compute body (hardware-proven, 88us,
//  absmax=0) + only the load-burst fix (launch_bounds + sched_barrier).
//  The u64-key single-round argmax is shelved until this result is in.]
//
// R6 post-mortem (88us best): lane = COLUMN, registers = rows; coalesced
// dword rows; no LDS/barriers; traffic exact; occupancy 66%; still
// latency-bound. Little's law: per-wave latency ~26us vs ~3us critical path.
// Root cause: VGPR_Count=28 for a kernel with float v[30] -> compiler chose
// minimal-liveness schedule (AGPR ping-pong, loads sunk to uses), killing
// the 30-deep load burst; in-flight bytes collapse, HBM latency exposed.
//
// Fix: __launch_bounds__(256,4) (VGPR budget 128) + sched_barrier(0) after
// the load loop -> all 30 loads issue back-to-back into real registers
// before any compute. Everything else identical to R6.

#define IMG_H 1080
#define IMG_W 1920

template <int K>
__device__ __forceinline__ void stage(float (&v)[30], int cg, int cc) {
    constexpr int NW = 30 / K;  // windows along the 30 rows
#pragma unroll
    for (int j = 0; j < NW; ++j) {
        // vertical K-max of my column (thread-local)
        float vm = v[j * K];
#pragma unroll
        for (int rr = 1; rr < K; ++rr) vm = fmaxf(vm, v[j * K + rr]);
        // horizontal max over the K columns of the group
        float M = vm;
#pragma unroll
        for (int q = 0; q < K; ++q) M = fmaxf(M, __shfl(vm, cg + q, 64));
        // equality mask over my column's K rows (exact fp compare)
        unsigned mask = 0u;
#pragma unroll
        for (int rr = 0; rr < K; ++rr)
            mask |= (v[j * K + rr] == M) ? (1u << rr) : 0u;
        // combine masks across the group; prefix = cols strictly before mine
        unsigned comb = 0u, pre = 0u;
#pragma unroll
        for (int q = 0; q < K; ++q) {
            const unsigned mq = (unsigned)__shfl((int)mask, cg + q, 64);
            comb |= mq;
            pre |= (q < cc) ? mq : 0u;
        }
        const int R = __ffs(comb) - 1;  // first row containing the max
        const bool win = ((mask >> R) & 1u) != 0u && ((pre >> R) & 1u) == 0u;
        // keep only the first (row-major) occurrence of the max
#pragma unroll
        for (int rr = 0; rr < K; ++rr)
            v[j * K + rr] = (win && rr == R) ? M : 0.0f;
    }
}

__global__ __launch_bounds__(256, 4) void pooling_nms_kernel(
    const float* __restrict__ x, float* __restrict__ out) {
    const int t = threadIdx.x;
    const int w = t >> 6;                  // wave 0..3 -> 60-col sub-strip
    const int lane = t & 63;
    const int c = (lane < 60) ? lane : 59; // idle lanes mirror col 59: loads
                                           // are in-bounds duplicates, compute
                                           // identical, stores predicated off.
                                           // Groups never source lanes >= 60.
    const int col0 = blockIdx.x * 240 + w * 60;
    const size_t base = (size_t)blockIdx.z * (IMG_H * (size_t)IMG_W) +
                        (size_t)(blockIdx.y * 30) * IMG_W + col0 + c;
    const float* src = x + base;
    float* dst = out + base;

    // Coalesced column load: per row, lanes 0..59 = 240 contiguous bytes.
    float v[30];
#pragma unroll
    for (int r = 0; r < 30; ++r) v[r] = src[(size_t)r * IMG_W];
    // Pin the 30-deep load burst above all compute (no sinking to uses).
    __builtin_amdgcn_sched_barrier(0);

    {   // stage K=3: groups {0,1,2},{3,4,5},... within 60 lanes
        const int cg = (c / 3) * 3;
        stage<3>(v, cg, c - cg);
    }
    {   // stage K=5
        const int cg = (c / 5) * 5;
        stage<5>(v, cg, c - cg);
    }
    {   // stage K=6
        const int cg = (c / 6) * 6;
        stage<6>(v, cg, c - cg);
    }

    if (lane < 60) {
#pragma unroll
        for (int r = 0; r < 30; ++r) dst[(size_t)r * IMG_W] = v[r];
    }
}

extern "C" void kernel_launch(void* const* d_in, const int* in_sizes, int n_in,
                              void* d_out, int out_size, void* d_ws, size_t ws_size,
                              hipStream_t stream) {
    const float* x = (const float*)d_in[0];
    float* out = (float*)d_out;
    dim3 grid(IMG_W / 240, IMG_H / 30, 16);  // 8 x 36 x 16 = 4608 blocks
    pooling_nms_kernel<<<grid, 256, 0, stream>>>(x, out);
}

// Round 10
// 238.100 us; speedup vs baseline: 1.0193x; 1.0193x over previous
//
#include <hip/hip_runtime.h>
#include <stdint.h>

// PoolingNms: 3 chained pool/unpool passes (k=3,5,6) on 16x1x1080x1920 fp32.
// lcm(3,5,6)=30 -> every 30x30 tile independent.
//
// R6/R9 (87-88us): lane = COLUMN, registers = rows; coalesced dword rows; no
// LDS/barriers; traffic exact; occupancy 64%. Latency-bound: VGPR_Count=28(!)
// -> compiler shunts v[30] through AGPRs, recycles few load-dest regs with
// tight vmcnt waits -> no load burst, serialized shuffle chains. R9 proved
// launch_bounds+sched_barrier alone do NOT raise register usage. Meanwhile
// fillBufferAligned in the same profile: 6.1 TB/s at 9% occupancy, 8 VGPR ->
// deep per-wave MLP is sufficient for BW on this chip; we have none.
//
// R10 fixes:
//  1. asm volatile "+v" pin of all 30 elements after the load loop: forces
//     30 live arch VGPRs -> real 30-deep load burst, VGPR-resident compute
//     (no accvgpr round-trips), registers available to overlap windows.
//     __launch_bounds__(256,6): cap ~80 VGPR (est ~60), 24 waves/CU.
//  2. ONE cross-lane gather round per window (u64 key as hi/lo u32 shuffles):
//     key = (bits<<6)|((7-vr)<<3)|(7-cc); max over group == row-major
//     first-occurrence argmax exactly (max value -> min row -> min col).
//     Replaces R9's two dependent rounds + ffs/prefix logic.
// Tie semantics: vertical ascending strict-'>' scan = FIRST row of column
// max; key low bits order ties (row, then col) ascending; values in [0,2)
// so float bits are order-isomorphic and fit 31 bits (hi = bits>>26 < 32).
// Stores plain (not nontemporal): L2 write-merge keeps WRITE_SIZE exact.

#define IMG_H 1080
#define IMG_W 1920

template <int K>
__device__ __forceinline__ void stage(float (&v)[30], int cg, int cc) {
    constexpr int NW = 30 / K;  // windows along the 30 rows
#pragma unroll
    for (int j = 0; j < NW; ++j) {
        // vertical scan, thread-local: column max + FIRST row achieving it
        float vm = v[j * K];
        int vr = 0;
#pragma unroll
        for (int rr = 1; rr < K; ++rr)
            if (v[j * K + rr] > vm) { vm = v[j * K + rr]; vr = rr; }
        // pack (value, row, col) into a 37-bit key held as hi:lo u32
        const unsigned b = __float_as_uint(vm);
        const unsigned lo = (b << 6) | (unsigned)((7 - vr) << 3) | (unsigned)(7 - cc);
        const unsigned hi = b >> 26;
        // horizontal: ONE gather round over the K group columns
        unsigned Mlo = lo, Mhi = hi;
#pragma unroll
        for (int q = 0; q < K; ++q) {
            const unsigned qlo = (unsigned)__shfl((int)lo, cg + q, 64);
            const unsigned qhi = (unsigned)__shfl((int)hi, cg + q, 64);
            if (qhi > Mhi || (qhi == Mhi && qlo > Mlo)) { Mhi = qhi; Mlo = qlo; }
        }
        // decode winner; cc bits make keys unique within the group
        const float val = __uint_as_float((Mhi << 26) | (Mlo >> 6));
        const int rwin = 7 - (int)((Mlo >> 3) & 7u);
        const bool colwin = (Mlo == lo) && (Mhi == hi);
#pragma unroll
        for (int rr = 0; rr < K; ++rr)
            v[j * K + rr] = (colwin && rr == rwin) ? val : 0.0f;
    }
}

__global__ __launch_bounds__(256, 6) void pooling_nms_kernel(
    const float* __restrict__ x, float* __restrict__ out) {
    const int t = threadIdx.x;
    const int w = t >> 6;                  // wave 0..3 -> 60-col sub-strip
    const int lane = t & 63;
    const int c = (lane < 60) ? lane : 59; // idle lanes mirror col 59: loads
                                           // in-bounds duplicates, compute
                                           // identical, stores predicated off.
                                           // Groups never source lanes >= 60.
    const int col0 = blockIdx.x * 240 + w * 60;
    const size_t base = (size_t)blockIdx.z * (IMG_H * (size_t)IMG_W) +
                        (size_t)(blockIdx.y * 30) * IMG_W + col0 + c;
    const float* src = x + base;
    float* dst = out + base;

    // Coalesced column load: per row, lanes 0..59 = 240 contiguous bytes.
    float v[30];
#pragma unroll
    for (int r = 0; r < 30; ++r) v[r] = src[(size_t)r * IMG_W];
    // Force all 30 values into live arch VGPRs HERE: the compiler must issue
    // all 30 loads (30-deep MLP) and keep results out of AGPRs.
    asm volatile("" :
        "+v"(v[0]), "+v"(v[1]), "+v"(v[2]), "+v"(v[3]), "+v"(v[4]),
        "+v"(v[5]), "+v"(v[6]), "+v"(v[7]), "+v"(v[8]), "+v"(v[9]),
        "+v"(v[10]), "+v"(v[11]), "+v"(v[12]), "+v"(v[13]), "+v"(v[14]),
        "+v"(v[15]), "+v"(v[16]), "+v"(v[17]), "+v"(v[18]), "+v"(v[19]),
        "+v"(v[20]), "+v"(v[21]), "+v"(v[22]), "+v"(v[23]), "+v"(v[24]),
        "+v"(v[25]), "+v"(v[26]), "+v"(v[27]), "+v"(v[28]), "+v"(v[29]));

    {   // stage K=3: groups {0,1,2},{3,4,5},... within 60 lanes
        const int cg = (c / 3) * 3;
        stage<3>(v, cg, c - cg);
    }
    {   // stage K=5
        const int cg = (c / 5) * 5;
        stage<5>(v, cg, c - cg);
    }
    {   // stage K=6
        const int cg = (c / 6) * 6;
        stage<6>(v, cg, c - cg);
    }

    if (lane < 60) {
#pragma unroll
        for (int r = 0; r < 30; ++r) dst[(size_t)r * IMG_W] = v[r];
    }
}

extern "C" void kernel_launch(void* const* d_in, const int* in_sizes, int n_in,
                              void* d_out, int out_size, void* d_ws, size_t ws_size,
                              hipStream_t stream) {
    const float* x = (const float*)d_in[0];
    float* out = (float*)d_out;
    dim3 grid(IMG_W / 240, IMG_H / 30, 16);  // 8 x 36 x 16 = 4608 blocks
    pooling_nms_kernel<<<grid, 256, 0, stream>>>(x, out);
}

// Round 11
// 233.289 us; speedup vs baseline: 1.0403x; 1.0206x over previous
//
#include <hip/hip_runtime.h>
#include <stdint.h>

// PoolingNms: 3 chained pool/unpool passes (k=3,5,6) on 16x1x1080x1920 fp32.
// lcm(3,5,6)=30 -> every 30x30 tile independent; 30x240 strips keep all
// global accesses 64B-line-aligned (R1 lesson: else WRITE_SIZE amplifies).
//
// R6-R10 post-mortem: lane=column compute is right, but the compiler pins
// the kernel at VGPR_Count=28 (loads recycled through ~6 dest regs with
// tight vmcnt waits; v[30] shunted via AGPRs) -> per-wave load MLP ~ none,
// per-wave latency ~24us vs ~3us critical path. Three coercion attempts
// (launch_bounds, sched_barrier, asm "+v" pin) all failed to move it.
// Control: fillBufferAligned = 6.1 TB/s @ 9% occupancy, 8 VGPR -> deep
// per-wave VMEM MLP is sufficient and occupancy is NOT the missing piece.
//
// R11: MLP without registers -> global_load_lds (dest needs no VGPRs).
//  - Block (4 waves) owns one strip in LDS, row stride 1024B.
//  - Load: ONE global_load_lds dwordx4 per row (60 lanes x 16B = 960B row),
//    rows round-robin over waves -> whole 28.8KB strip in flight per block,
//    ~144KB in flight per CU at 5 blocks/CU. One __syncthreads (vmcnt(0)
//    drain is exactly what we need here).
//  - Compute: R6's proven stage body UNCHANGED (lane=column, v[30], group
//    shuffles), fed by ds_read (~120cyc) instead of HBM (~900cyc); sub-strips
//    wave-private -> no barriers inside stages.
//  - Writeback to LDS (wave-private), one barrier, coalesced dwordx4 stores
//    (960B rows, line-aligned, partial lines never cross blocks).
// Tie semantics unchanged from R6 (absmax=0 on HW): horizontal max round +
// mask round; first row via __ffs of OR'd masks, first col via prefix mask.

#define IMG_H 1080
#define IMG_W 1920
#define TH 30
#define TW 240
#define LSTRIDE 256   // LDS row stride in floats (1024 B)
#define NTHREADS 256

#define GPTR(p) ((const __attribute__((address_space(1))) void*)(p))
#define LPTR(p) ((__attribute__((address_space(3))) void*)(p))

template <int K>
__device__ __forceinline__ void stage(float (&v)[30], int cg, int cc) {
    constexpr int NW = 30 / K;  // windows along the 30 rows
#pragma unroll
    for (int j = 0; j < NW; ++j) {
        // vertical K-max of my column (thread-local)
        float vm = v[j * K];
#pragma unroll
        for (int rr = 1; rr < K; ++rr) vm = fmaxf(vm, v[j * K + rr]);
        // horizontal max over the K columns of the group
        float M = vm;
#pragma unroll
        for (int q = 0; q < K; ++q) M = fmaxf(M, __shfl(vm, cg + q, 64));
        // equality mask over my column's K rows (exact fp compare)
        unsigned mask = 0u;
#pragma unroll
        for (int rr = 0; rr < K; ++rr)
            mask |= (v[j * K + rr] == M) ? (1u << rr) : 0u;
        // combine masks across the group; prefix = cols strictly before mine
        unsigned comb = 0u, pre = 0u;
#pragma unroll
        for (int q = 0; q < K; ++q) {
            const unsigned mq = (unsigned)__shfl((int)mask, cg + q, 64);
            comb |= mq;
            pre |= (q < cc) ? mq : 0u;
        }
        const int R = __ffs(comb) - 1;  // first row containing the max
        const bool win = ((mask >> R) & 1u) != 0u && ((pre >> R) & 1u) == 0u;
        // keep only the first (row-major) occurrence of the max
#pragma unroll
        for (int rr = 0; rr < K; ++rr)
            v[j * K + rr] = (win && rr == R) ? M : 0.0f;
    }
}

__global__ __launch_bounds__(NTHREADS) void pooling_nms_kernel(
    const float* __restrict__ x, float* __restrict__ out) {
    __shared__ float tile[TH * LSTRIDE];  // 30720 B -> 5 blocks/CU

    const int t = threadIdx.x;
    const int w = t >> 6;                  // wave 0..3
    const int lane = t & 63;
    const int c = (lane < 60) ? lane : 59; // compute col within sub-strip;
                                           // lanes 60-63 mirror col 59 (same
                                           // data, same shuffles; writeback &
                                           // stores predicated off; groups
                                           // never source lanes >= 60)

    const size_t base = (size_t)blockIdx.z * (IMG_H * (size_t)IMG_W) +
                        (size_t)(blockIdx.y * TH) * IMG_W + blockIdx.x * TW;
    const float* src = x + base;
    float* dst = out + base;

    // ---- Load: one dwordx4 global_load_lds per row (60 lanes x 16B = 960B).
    // Register-free -> the whole strip (28.8 KB) goes in flight at once.
    if (lane < 60) {
        for (int r = w; r < TH; r += 4)
            __builtin_amdgcn_global_load_lds(
                GPTR(src + (size_t)r * IMG_W + lane * 4),
                LPTR(&tile[r * LSTRIDE + lane * 4]), 16, 0, 0);
    }
    __syncthreads();  // vmcnt(0)+barrier: all waves' loads visible

    // ---- Compute: wave w owns cols [60w, 60w+60) = two independent
    // 30-col groups; lane c = its column. Wave-private -> no barriers.
    const int colw = 60 * w + c;
    float v[30];
#pragma unroll
    for (int r = 0; r < TH; ++r) v[r] = tile[r * LSTRIDE + colw];

    {   // stage K=3: groups {0,1,2},{3,4,5},... within the 60 lanes
        const int cg = (c / 3) * 3;
        stage<3>(v, cg, c - cg);
    }
    {   // stage K=5
        const int cg = (c / 5) * 5;
        stage<5>(v, cg, c - cg);
    }
    {   // stage K=6
        const int cg = (c / 6) * 6;
        stage<6>(v, cg, c - cg);
    }

    if (lane < 60) {
#pragma unroll
        for (int r = 0; r < TH; ++r) tile[r * LSTRIDE + colw] = v[r];
    }
    __syncthreads();  // writeback visible to all waves

    // ---- Store: coalesced dwordx4; wave w stores rows w, w+4, ...
    // Row base = base + r*7680 + bx*960: 960 % 64 == 0 -> line-aligned,
    // partial lines never shared across blocks -> no write amplification.
    if (lane < 60) {
        for (int r = w; r < TH; r += 4) {
            const float4 val =
                *reinterpret_cast<const float4*>(&tile[r * LSTRIDE + lane * 4]);
            *reinterpret_cast<float4*>(dst + (size_t)r * IMG_W + lane * 4) = val;
        }
    }
}

extern "C" void kernel_launch(void* const* d_in, const int* in_sizes, int n_in,
                              void* d_out, int out_size, void* d_ws, size_t ws_size,
                              hipStream_t stream) {
    const float* x = (const float*)d_in[0];
    float* out = (float*)d_out;
    dim3 grid(IMG_W / TW, IMG_H / TH, 16);  // 8 x 36 x 16 = 4608 blocks
    pooling_nms_kernel<<<grid, NTHREADS, 0, stream>>>(x, out);
}